// Round 10
// baseline (7542.858 us; speedup 1.0000x reference)
//
#include <hip/hip_runtime.h>

#define BATCH 128
#define NUSERS 50000
#define PW 16   // plane width (cols per slice)
#define NSL 8   // slices

// ---- non-temporal helpers (streaming accesses must not evict L2-resident planes) ----
__device__ __forceinline__ int2 nt_load_i2(const int2* p) {
  unsigned long long L = __builtin_nontemporal_load((const unsigned long long*)p);
  return make_int2((int)(unsigned)L, (int)(unsigned)(L >> 32));
}
__device__ __forceinline__ float2 nt_load_f2(const float* p) {
  unsigned long long L = __builtin_nontemporal_load((const unsigned long long*)p);
  float2 r;
  r.x = __uint_as_float((unsigned)L);
  r.y = __uint_as_float((unsigned)(L >> 32));
  return r;
}
__device__ __forceinline__ void nt_store_f2(float* p, float2 v) {
  unsigned long long L = (unsigned long long)__float_as_uint(v.x) |
                         ((unsigned long long)__float_as_uint(v.y) << 32);
  __builtin_nontemporal_store(L, (unsigned long long*)p);
}

// ---------------- fused histogram (rows + cols in one pass) ----------------
__global__ void hist2_k(const int* __restrict__ rows, const int* __restrict__ cols,
                        int* __restrict__ histU, int* __restrict__ histI, int nnz) {
  int i = blockIdx.x * blockDim.x + threadIdx.x;
  int st = gridDim.x * blockDim.x;
  for (; i < nnz; i += st) {
    atomicAdd(&histU[rows[i]], 1);
    atomicAdd(&histI[cols[i]], 1);
  }
}

// ---------------- exclusive scan (single block, 1024 threads) ----------------
__global__ void scan_k(const int* __restrict__ hist, int* __restrict__ offs,
                       int* __restrict__ cursor, int n) {
  __shared__ int wsum[16];
  __shared__ int carry;
  int tid = threadIdx.x;
  int lane = tid & 63;
  int wv = tid >> 6;
  if (tid == 0) carry = 0;
  __syncthreads();
  for (int base = 0; base < n; base += 1024) {
    int i = base + tid;
    int x = (i < n) ? hist[i] : 0;
    int incl = x;
#pragma unroll
    for (int d = 1; d < 64; d <<= 1) {
      int y = __shfl_up(incl, (unsigned)d, 64);
      if (lane >= d) incl += y;
    }
    if (lane == 63) wsum[wv] = incl;
    __syncthreads();
    if (wv == 0) {
      int t = (lane < 16) ? wsum[lane] : 0;
#pragma unroll
      for (int d = 1; d < 16; d <<= 1) {
        int y = __shfl_up(t, (unsigned)d, 64);
        if (lane >= d) t += y;
      }
      if (lane < 16) wsum[lane] = t;
    }
    __syncthreads();
    int woff = (wv > 0) ? wsum[wv - 1] : 0;
    int excl = carry + woff + incl - x;
    if (i < n) { offs[i] = excl; cursor[i] = excl; }
    int chunk_total = wsum[15];
    __syncthreads();
    if (tid == 0) carry += chunk_total;
    __syncthreads();
  }
  if (tid == 0) offs[n] = carry;
}

// ---------------- fused dual scatter: COO -> CSR ev + CSC ev ----------------
__global__ void scatter2_k(const int* __restrict__ rows, const int* __restrict__ cols,
                           const float* __restrict__ vals, int* __restrict__ curU,
                           int* __restrict__ curI, int2* __restrict__ csr_ev,
                           int2* __restrict__ csc_ev, int nnz) {
  int i = blockIdx.x * blockDim.x + threadIdx.x;
  int st = gridDim.x * blockDim.x;
  for (; i < nnz; i += st) {
    int r = rows[i], c = cols[i];
    int vb = __float_as_int(vals[i]);
    int p = atomicAdd(&curU[r], 1);
    csr_ev[p] = make_int2(c, vb);
    int q = atomicAdd(&curI[c], 1);
    csc_ev[q] = make_int2(r, vb);
  }
}

// ---------------- T0/acc init, plane-major: T0[p][item][16] ----------------
__global__ void transpose_init_k(const float* __restrict__ Xb, const float* __restrict__ coeffs,
                                 float* __restrict__ T0, float* __restrict__ acc, int nitems) {
  __shared__ float t[16][17];
  int tx = threadIdx.x, ty = threadIdx.y;
  int p = blockIdx.y;
  int i0 = blockIdx.x * 16;
  t[ty][tx] = Xb[(size_t)(p * 16 + ty) * nitems + i0 + tx];
  __syncthreads();
  float c0 = coeffs[0];
  float v = t[tx][ty];  // (item=i0+ty, col-in-plane=tx)
  size_t o = (size_t)p * nitems * PW + (size_t)(i0 + ty) * PW + tx;
  T0[o] = v;
  acc[o] = c0 * v;
}

// ---------------- out[b][item] from acc planes ----------------
__global__ void transpose_out_k(const float* __restrict__ acc, float* __restrict__ out, int nitems) {
  __shared__ float t[16][17];
  int tx = threadIdx.x, ty = threadIdx.y;
  int p = blockIdx.y;
  int i0 = blockIdx.x * 16;
  t[ty][tx] = acc[(size_t)p * nitems * PW + (size_t)(i0 + ty) * PW + tx];
  __syncthreads();
  out[(size_t)(p * 16 + ty) * nitems + i0 + tx] = t[tx][ty];
}

// ---------------- phase A: u_plane[s] = X * v_plane[s] ----------------
// slice s = blockIdx & 7 (XCD round-robin); 8-lane slots, 32 rows/block.
// ev: nt (streaming). v gathers: normal (L2-resident plane). u out: nt.
__global__ void __launch_bounds__(256) spmm_u_k(const int* __restrict__ offs,
                                                const int2* __restrict__ ev,
                                                const float* __restrict__ v,
                                                float* __restrict__ u,
                                                int nrows, size_t vstride, size_t ustride) {
  int s = blockIdx.x & 7;
  int g = blockIdx.x >> 3;
  int slot = threadIdx.x >> 3;
  int lane8 = threadIdx.x & 7;
  int row = g * 32 + slot;
  if (row >= nrows) return;
  int k0 = offs[row], k1 = offs[row + 1];
  const float* vp = v + (size_t)s * vstride + (lane8 << 1);
  float2 a = {0.f, 0.f};
  int base = threadIdx.x & ~7;
  for (int k = k0; k < k1; k += 8) {
    int kk = k + lane8;
    int2 e = (kk < k1) ? nt_load_i2(&ev[kk]) : make_int2(0, 0);
#pragma unroll
    for (int j = 0; j < 8; j++) {
      int src = base | j;
      int idx = __shfl(e.x, src);
      float w = __int_as_float(__shfl(e.y, src));
      float2 x = *reinterpret_cast<const float2*>(vp + ((size_t)idx << 4));
      a.x = fmaf(w, x.x, a.x);
      a.y = fmaf(w, x.y, a.y);
    }
  }
  nt_store_f2(u + (size_t)s * ustride + ((size_t)row << 4) + (lane8 << 1), a);
}

// ---------------- phase B: w_plane[s] = X^T * u_plane[s]; fused Chebyshev ----------------
// ev/vcur/tio/acc: nt (streaming). u gathers: normal (L2-resident plane).
__global__ void __launch_bounds__(256) spmm_i_cheb_k(const int* __restrict__ offs,
                                                     const int2* __restrict__ ev,
                                                     const float* __restrict__ u,
                                                     const float* __restrict__ vcur,
                                                     float* __restrict__ tio,
                                                     float* __restrict__ acc,
                                                     const float* __restrict__ t_mid,
                                                     const float* __restrict__ t_half,
                                                     const float* __restrict__ coeffs,
                                                     int cix, float sA, float sB,
                                                     int nitems, size_t ustride, size_t tstride) {
  int s = blockIdx.x & 7;
  int g = blockIdx.x >> 3;
  int slot = threadIdx.x >> 3;
  int lane8 = threadIdx.x & 7;
  int item = g * 32 + slot;
  if (item >= nitems) return;
  int k0 = offs[item], k1 = offs[item + 1];
  const float* up = u + (size_t)s * ustride + (lane8 << 1);
  float2 w = {0.f, 0.f};
  int base = threadIdx.x & ~7;
  for (int k = k0; k < k1; k += 8) {
    int kk = k + lane8;
    int2 e = (kk < k1) ? nt_load_i2(&ev[kk]) : make_int2(0, 0);
#pragma unroll
    for (int j = 0; j < 8; j++) {
      int src = base | j;
      int idx = __shfl(e.x, src);
      float wv = __int_as_float(__shfl(e.y, src));
      float2 x = *reinterpret_cast<const float2*>(up + ((size_t)idx << 4));
      w.x = fmaf(wv, x.x, w.x);
      w.y = fmaf(wv, x.y, w.y);
    }
  }
  float mid = t_mid[0];
  float inv = 1.0f / t_half[0];
  float c = coeffs[cix];
  size_t idx = (size_t)s * tstride + ((size_t)item << 4) + (lane8 << 1);
  float2 vv = nt_load_f2(vcur + idx);
  float2 t;
  t.x = (w.x - mid * vv.x) * inv;
  t.y = (w.y - mid * vv.y) * inv;
  if (sB != 0.0f) {
    float2 p = nt_load_f2(tio + idx);
    t.x = sA * t.x - sB * p.x;
    t.y = sA * t.y - sB * p.y;
  }
  nt_store_f2(tio + idx, t);
  float2 a = nt_load_f2(acc + idx);
  a.x = fmaf(c, t.x, a.x);
  a.y = fmaf(c, t.y, a.y);
  nt_store_f2(acc + idx, a);
}

extern "C" void kernel_launch(void* const* d_in, const int* in_sizes, int n_in,
                              void* d_out, int out_size, void* d_ws, size_t ws_size,
                              hipStream_t stream) {
  const float* Xb     = (const float*)d_in[0];
  const float* vals   = (const float*)d_in[1];
  const float* coeffs = (const float*)d_in[2];
  const float* t_mid  = (const float*)d_in[3];
  const float* t_half = (const float*)d_in[4];
  const int*   rows   = (const int*)d_in[5];
  const int*   cols   = (const int*)d_in[6];

  int nnz    = in_sizes[1];
  int nitems = in_sizes[0] / BATCH;   // 20000
  int nusers = NUSERS;                // 50000
  int ncoef  = in_sizes[2];           // 21

  size_t vstride = (size_t)nitems * PW;
  size_t ustride = (size_t)nusers * PW;

  char* base = (char*)d_ws;
  size_t o = 0;
  auto alloc = [&](size_t bytes) -> void* {
    void* p = base + o;
    o = (o + bytes + 255) & ~(size_t)255;
    return p;
  };
  int2*  csr_ev   = (int2*)alloc((size_t)nnz * 8);
  int2*  csc_ev   = (int2*)alloc((size_t)nnz * 8);
  int*   csr_offs = (int*)alloc((size_t)(nusers + 1) * 4);
  int*   csc_offs = (int*)alloc((size_t)(nitems + 1) * 4);
  int*   curU     = (int*)alloc((size_t)(nusers + 1) * 4);
  int*   curI     = (int*)alloc((size_t)(nitems + 1) * 4);
  int*   histU    = (int*)alloc((size_t)(nusers + 1) * 4);
  int*   histI    = (int*)alloc((size_t)(nitems + 1) * 4);
  float* u        = (float*)alloc((size_t)NSL * ustride * 4);
  float* Ta       = (float*)alloc((size_t)NSL * vstride * 4);
  float* Tb       = (float*)alloc((size_t)NSL * vstride * 4);
  float* accb     = (float*)alloc((size_t)NSL * vstride * 4);
  (void)ws_size;

  hipMemsetAsync(histU, 0, (size_t)(nusers + 1) * 4, stream);
  hipMemsetAsync(histI, 0, (size_t)(nitems + 1) * 4, stream);
  hist2_k<<<2048, 256, 0, stream>>>(rows, cols, histU, histI, nnz);
  scan_k<<<1, 1024, 0, stream>>>(histU, csr_offs, curU, nusers);
  scan_k<<<1, 1024, 0, stream>>>(histI, csc_offs, curI, nitems);
  scatter2_k<<<2048, 256, 0, stream>>>(rows, cols, vals, curU, curI, csr_ev, csc_ev, nnz);

  dim3 tb16(16, 16);
  transpose_init_k<<<dim3(nitems / 16, BATCH / 16), tb16, 0, stream>>>(Xb, coeffs, Ta, accb, nitems);

  int ublocks = ((nusers + 31) / 32) * NSL;
  int iblocks = ((nitems + 31) / 32) * NSL;

  spmm_u_k<<<ublocks, 256, 0, stream>>>(csr_offs, csr_ev, Ta, u, nusers, vstride, ustride);
  spmm_i_cheb_k<<<iblocks, 256, 0, stream>>>(csc_offs, csc_ev, u, Ta, Tb, accb,
                                             t_mid, t_half, coeffs, 1, 1.0f, 0.0f,
                                             nitems, ustride, vstride);
  float* Tp = Ta;
  float* Tc = Tb;
  for (int s = 2; s < ncoef; ++s) {
    spmm_u_k<<<ublocks, 256, 0, stream>>>(csr_offs, csr_ev, Tc, u, nusers, vstride, ustride);
    spmm_i_cheb_k<<<iblocks, 256, 0, stream>>>(csc_offs, csc_ev, u, Tc, Tp, accb,
                                               t_mid, t_half, coeffs, s, 2.0f, 1.0f,
                                               nitems, ustride, vstride);
    float* tmp = Tp; Tp = Tc; Tc = tmp;
  }

  transpose_out_k<<<dim3(nitems / 16, BATCH / 16), tb16, 0, stream>>>(accb, (float*)d_out, nitems);
}